// Round 1
// baseline (1690.858 us; speedup 1.0000x reference)
//
#include <hip/hip_runtime.h>
#include <hip/hip_bf16.h>

// Problem constants
#define B_  32
#define S_  1024
#define H_  512      // == F
#define ML_ 4096

constexpr int TS   = 16;          // sequence rows per conv block
constexpr int LROW = 516;         // padded LDS row stride (floats), 516*4 % 16 == 0

// Output layout (flat float32):
//   expanded : [0, 67108864)
//   log_dur  : +32768
//   dur      : +32768
//   tgt_len  : +32
//   tgt_mask : +131072
constexpr size_t OFF_LOGDUR = (size_t)B_ * ML_ * H_;        // 67108864
constexpr size_t OFF_DUR    = OFF_LOGDUR + (size_t)B_ * S_;
constexpr size_t OFF_TLEN   = OFF_DUR + (size_t)B_ * S_;
constexpr size_t OFF_TMASK  = OFF_TLEN + B_;

__device__ __forceinline__ float wave_red(float v) {
#pragma unroll
    for (int o = 32; o > 0; o >>= 1) v += __shfl_down(v, o, 64);
    return v;
}

// Fused conv1d(K=3, SAME) + bias + ReLU + LayerNorm.
// LOGDUR=false: writes LN output (B*S*512).
// LOGDUR=true : skips writing h2; fuses the lin_w dot product + mask into log_dur.
template <bool LOGDUR>
__global__ __launch_bounds__(256, 4) void conv_ln_kernel(
    const float* __restrict__ in, const float* __restrict__ W,
    const float* __restrict__ bias, const float* __restrict__ gamma,
    const float* __restrict__ beta, float* __restrict__ out,
    const float* __restrict__ lin_w, const float* __restrict__ lin_b,
    const int* __restrict__ src_lens, float* __restrict__ log_dur) {
    const int b   = blockIdx.y;
    const int s0  = blockIdx.x * TS;
    const int tid = threadIdx.x;

    __shared__ float lds[(TS + 2) * LROW];
    __shared__ float red1[TS][4], red2[TS][4], red3[TS][4];

    // Stage TS+2 input rows (with zero SAME-padding at batch edges)
    {
        const float4* src = (const float4*)in;
        for (int i = tid; i < (TS + 2) * (H_ / 4); i += 256) {
            int r = i >> 7;          // H_/4 == 128
            int c = i & 127;
            int s = s0 - 1 + r;
            float4 v = make_float4(0.f, 0.f, 0.f, 0.f);
            if (s >= 0 && s < S_) v = src[(size_t)(b * S_ + s) * (H_ / 4) + c];
            *(float4*)&lds[r * LROW + c * 4] = v;
        }
    }
    __syncthreads();

    const int f0 = tid * 2;
    float acc[TS][2];
#pragma unroll
    for (int t = 0; t < TS; ++t) { acc[t][0] = 0.f; acc[t][1] = 0.f; }

    const float* Wf = W + f0;
    for (int h = 0; h < H_; ++h) {
        float iv[TS + 2];
#pragma unroll
        for (int r = 0; r < TS + 2; ++r) iv[r] = lds[r * LROW + h];
#pragma unroll
        for (int k = 0; k < 3; ++k) {
            const float2 w = *(const float2*)(Wf + (size_t)(k * H_ + h) * 512);
#pragma unroll
            for (int t = 0; t < TS; ++t) {
                acc[t][0] = fmaf(iv[t + k], w.x, acc[t][0]);
                acc[t][1] = fmaf(iv[t + k], w.y, acc[t][1]);
            }
        }
    }

    // bias + ReLU
    const float2 bb = *(const float2*)(bias + f0);
#pragma unroll
    for (int t = 0; t < TS; ++t) {
        acc[t][0] = fmaxf(acc[t][0] + bb.x, 0.f);
        acc[t][1] = fmaxf(acc[t][1] + bb.y, 0.f);
    }

    // per-row sum / sum-of-squares reduction (wave shuffle + 4-slot LDS)
    const int wv = tid >> 6, lane = tid & 63;
#pragma unroll
    for (int t = 0; t < TS; ++t) {
        float s1 = wave_red(acc[t][0] + acc[t][1]);
        float s2 = wave_red(acc[t][0] * acc[t][0] + acc[t][1] * acc[t][1]);
        if (lane == 0) { red1[t][wv] = s1; red2[t][wv] = s2; }
    }
    __syncthreads();

    const float2 gg = *(const float2*)(gamma + f0);
    const float2 be = *(const float2*)(beta + f0);
    float2 lw = make_float2(0.f, 0.f);
    if (LOGDUR) lw = *(const float2*)(lin_w + f0);

#pragma unroll
    for (int t = 0; t < TS; ++t) {
        float mu   = (red1[t][0] + red1[t][1] + red1[t][2] + red1[t][3]) * (1.f / 512.f);
        float ex2  = (red2[t][0] + red2[t][1] + red2[t][2] + red2[t][3]) * (1.f / 512.f);
        float rstd = rsqrtf(ex2 - mu * mu + 1e-5f);
        float y0 = (acc[t][0] - mu) * rstd * gg.x + be.x;
        float y1 = (acc[t][1] - mu) * rstd * gg.y + be.y;
        if constexpr (!LOGDUR) {
            *(float2*)&out[(size_t)(b * S_ + s0 + t) * 512 + f0] = make_float2(y0, y1);
        } else {
            float p = wave_red(y0 * lw.x + y1 * lw.y);
            if (lane == 0) red3[t][wv] = p;
        }
    }

    if constexpr (LOGDUR) {
        __syncthreads();
        if (tid < TS) {
            int s = s0 + tid;
            float v = red3[tid][0] + red3[tid][1] + red3[tid][2] + red3[tid][3] + lin_b[0];
            log_dur[b * S_ + s] = (s >= src_lens[b]) ? 0.f : v;
        }
    }
}

// Per-batch: masked dur (as float), inclusive cumsum (int, to ws),
// tgt_len (float), tgt_mask (float 0/1).
__global__ __launch_bounds__(256) void scan_kernel(
    const int* __restrict__ duration, const int* __restrict__ src_lens,
    int* __restrict__ csum, float* __restrict__ dur_out,
    float* __restrict__ tlen_out, float* __restrict__ tmask_out) {
    const int b = blockIdx.x, t = threadIdx.x;
    __shared__ int lds[256];
    __shared__ int total_sh;

    const int slen = src_lens[b];
    int loc[4];
    const int sb = t * 4;
#pragma unroll
    for (int i = 0; i < 4; ++i) {
        int s = sb + i;
        loc[i] = (s < slen) ? duration[b * S_ + s] : 0;
    }
    int tsum = loc[0] + loc[1] + loc[2] + loc[3];

    lds[t] = tsum;
    __syncthreads();
    for (int off = 1; off < 256; off <<= 1) {
        int v = (t >= off) ? lds[t - off] : 0;
        __syncthreads();
        lds[t] += v;
        __syncthreads();
    }
    int incl = lds[t];
    if (t == 255) total_sh = incl;

    int run = incl - tsum;
#pragma unroll
    for (int i = 0; i < 4; ++i) {
        run += loc[i];
        csum[b * S_ + sb + i]   = run;
        dur_out[b * S_ + sb + i] = (float)loc[i];
    }
    __syncthreads();
    const int total = total_sh;
    if (t == 0) tlen_out[b] = (float)total;
    for (int p = t; p < ML_; p += 256) tmask_out[b * ML_ + p] = (p >= total) ? 1.f : 0.f;
}

// expanded[b,p,:] = (p < tgt_len) ? x[b, searchsorted(csum,p,'right') clipped, :] : 0
__global__ __launch_bounds__(256) void expand_kernel(
    const float* __restrict__ x, const int* __restrict__ csum,
    float* __restrict__ out) {
    const int tid  = threadIdx.x;
    const int row  = blockIdx.x * 2 + (tid >> 7);   // [0, B*ML)
    const int lane = tid & 127;
    const int b = row >> 12;                        // ML = 4096
    const int p = row & (ML_ - 1);

    const int* cs = csum + b * S_;
    const int total = cs[S_ - 1];

    int lo = 0, hi = S_;
    while (lo < hi) {
        int mid = (lo + hi) >> 1;
        if (cs[mid] <= p) lo = mid + 1; else hi = mid;
    }
    int idx = lo < (S_ - 1) ? lo : (S_ - 1);

    float4 v = make_float4(0.f, 0.f, 0.f, 0.f);
    if (p < total) v = ((const float4*)x)[(size_t)(b * S_ + idx) * (H_ / 4) + lane];
    ((float4*)out)[(size_t)row * (H_ / 4) + lane] = v;
}

extern "C" void kernel_launch(void* const* d_in, const int* in_sizes, int n_in,
                              void* d_out, int out_size, void* d_ws, size_t ws_size,
                              hipStream_t stream) {
    const float* x        = (const float*)d_in[0];
    const int*   duration = (const int*)d_in[1];
    const int*   src_lens = (const int*)d_in[2];
    // d_in[3] = src_mask (bool) — recomputed from src_lens instead
    const float* conv1_w = (const float*)d_in[4];
    const float* conv1_b = (const float*)d_in[5];
    const float* ln1_g   = (const float*)d_in[6];
    const float* ln1_b   = (const float*)d_in[7];
    const float* conv2_w = (const float*)d_in[8];
    const float* conv2_b = (const float*)d_in[9];
    const float* ln2_g   = (const float*)d_in[10];
    const float* ln2_b   = (const float*)d_in[11];
    const float* lin_w   = (const float*)d_in[12];
    const float* lin_b   = (const float*)d_in[13];

    float* out      = (float*)d_out;
    float* expanded = out;
    float* log_dur  = out + OFF_LOGDUR;
    float* dur_out  = out + OFF_DUR;
    float* tlen_out = out + OFF_TLEN;
    float* tmask    = out + OFF_TMASK;
    int*   csum     = (int*)d_ws;        // 32*1024 ints = 128 KB

    // h1 staged inside the (later overwritten) expanded region of d_out
    float* h1 = expanded;

    dim3 cgrid(S_ / TS, B_);
    conv_ln_kernel<false><<<cgrid, 256, 0, stream>>>(
        x, conv1_w, conv1_b, ln1_g, ln1_b, h1, nullptr, nullptr, nullptr, nullptr);
    conv_ln_kernel<true><<<cgrid, 256, 0, stream>>>(
        h1, conv2_w, conv2_b, ln2_g, ln2_b, nullptr, lin_w, lin_b, src_lens, log_dur);
    scan_kernel<<<B_, 256, 0, stream>>>(duration, src_lens, csum, dur_out, tlen_out, tmask);
    expand_kernel<<<B_ * ML_ / 2, 256, 0, stream>>>(x, csum, expanded);
}

// Round 2
// 513.563 us; speedup vs baseline: 3.2924x; 3.2924x over previous
//
#include <hip/hip_runtime.h>
#include <hip/hip_bf16.h>

#define B_  32
#define S_  1024
#define H_  512      // == F
#define ML_ 4096

typedef short short8 __attribute__((ext_vector_type(8)));
typedef float floatx4 __attribute__((ext_vector_type(4)));

// ---- output layout (flat float32 view) ----
constexpr size_t OFF_LOGDUR = (size_t)B_ * ML_ * H_;        // 67108864
constexpr size_t OFF_DUR    = OFF_LOGDUR + (size_t)B_ * S_;
constexpr size_t OFF_TLEN   = OFF_DUR + (size_t)B_ * S_;
constexpr size_t OFF_TMASK  = OFF_TLEN + B_;

// ---- scratch staged inside d_out's expanded region (bytes) ----
// expanded region = 268 MB, overwritten last by expand_kernel
constexpr size_t XP_BYTES = (size_t)B_ * 1026 * 512 * 2;    // 33,619,968
constexpr size_t WT_BYTES = (size_t)3 * 512 * 512 * 2;      // 1,572,864
constexpr size_t OFF_XP   = 0;
constexpr size_t OFF_H1P  = XP_BYTES;
constexpr size_t OFF_WT1  = 2 * XP_BYTES;
constexpr size_t OFF_WT2  = 2 * XP_BYTES + WT_BYTES;        // ends ~70.4 MB < 268 MB

__device__ __forceinline__ float wave_red(float v) {
#pragma unroll
    for (int o = 32; o > 0; o >>= 1) v += __shfl_down(v, o, 64);
    return v;
}

__device__ __forceinline__ unsigned short f2b(float f) {
    __hip_bfloat16 h = __float2bfloat16(f);
    return *reinterpret_cast<unsigned short*>(&h);
}

// async global->LDS, 16B per lane; LDS dst = wave-uniform base + lane*16
__device__ __forceinline__ void gld16(const void* g, void* l) {
    __builtin_amdgcn_global_load_lds(
        (const __attribute__((address_space(1))) unsigned int*)g,
        (__attribute__((address_space(3))) unsigned int*)l, 16, 0, 0);
}

// ===================== prep kernels =====================

// fp32 x -> bf16 Xp[b][1026][512] (interior rows; +1 row shift for halo)
__global__ __launch_bounds__(256) void cast_x_kernel(
    const float* __restrict__ x, unsigned short* __restrict__ Xp) {
    size_t gid = (size_t)blockIdx.x * 256 + threadIdx.x;
    size_t i8  = gid * 8;
    int row = (int)(i8 >> 9);
    int col = (int)(i8 & 511);
    int b = row >> 10, s = row & 1023;
    float4 v0 = *(const float4*)(x + i8);
    float4 v1 = *(const float4*)(x + i8 + 4);
    unsigned short u[8];
    u[0] = f2b(v0.x); u[1] = f2b(v0.y); u[2] = f2b(v0.z); u[3] = f2b(v0.w);
    u[4] = f2b(v1.x); u[5] = f2b(v1.y); u[6] = f2b(v1.z); u[7] = f2b(v1.w);
    *(uint4*)(Xp + ((size_t)b * 1026 + 1 + s) * 512 + col) = *(const uint4*)u;
}

// zero halo rows (row 0 and row 1025 of each batch) of Xp and H1p
__global__ __launch_bounds__(256) void zero_halos_kernel(
    unsigned short* __restrict__ Xp, unsigned short* __restrict__ H1p) {
    int b = blockIdx.x >> 1;
    unsigned short* p = (blockIdx.x & 1) ? H1p : Xp;
    int t = threadIdx.x;
    if (t < 128) {
        int r   = (t >> 6) ? 1025 : 0;
        int sgm = t & 63;
        uint4 z; z.x = 0; z.y = 0; z.z = 0; z.w = 0;
        *(uint4*)(p + ((size_t)(b * 1026 + r)) * 512 + sgm * 8) = z;
    }
}

// W[k][h][f] fp32 -> Wt[k][f][h] bf16
__global__ __launch_bounds__(256) void transpose_w_kernel(
    const float* __restrict__ W, unsigned short* __restrict__ Wt) {
    __shared__ float t[32][33];
    int k  = blockIdx.z;
    int h0 = blockIdx.x * 32, f0 = blockIdx.y * 32;
    int tx = threadIdx.x & 31, ty = threadIdx.x >> 5;
    const float* Wk = W + (size_t)k * 512 * 512;
    unsigned short* Wtk = Wt + (size_t)k * 512 * 512;
#pragma unroll
    for (int i = 0; i < 4; ++i)
        t[ty + 8 * i][tx] = Wk[(size_t)(h0 + ty + 8 * i) * 512 + f0 + tx];
    __syncthreads();
#pragma unroll
    for (int i = 0; i < 4; ++i)
        Wtk[(size_t)(f0 + ty + 8 * i) * 512 + h0 + tx] = f2b(t[tx][ty + 8 * i]);
}

// sum(g*lw), sum(be*lw) for the conv2 log_dur fold
__global__ __launch_bounds__(64) void sums_kernel(
    const float* __restrict__ g, const float* __restrict__ be,
    const float* __restrict__ lw, float* __restrict__ out) {
    int t = threadIdx.x;
    float a = 0.f, c = 0.f;
    for (int f = t; f < 512; f += 64) { a += g[f] * lw[f]; c += be[f] * lw[f]; }
    a = wave_red(a); c = wave_red(c);
    if (t == 0) { out[0] = a; out[1] = c; }
}

// ===================== fused conv+bias+ReLU+LN (bf16 MFMA) =====================
// Block: 64 (s-rows) x 512 (all f)  -> LN fully in-block.
// K-loop: 24 iters = 3 shifts (conv taps) x 8 h-chunks of 64.
// A tile 64x64 bf16 (8 KB), B tile 512x64 bf16 (64 KB), XOR-swizzled 16B slots.
template <bool LOGDUR>
__global__ __launch_bounds__(256, 2) void conv_mfma_kernel(
    const unsigned short* __restrict__ Xp,   // [B][1026][512] padded bf16
    const unsigned short* __restrict__ Wt,   // [3][512][512] f-major bf16
    const float* __restrict__ bias,
    const float* __restrict__ gamma,
    const float* __restrict__ beta,
    unsigned short* __restrict__ Op,         // conv1: padded bf16 out
    const float* __restrict__ lin_w,
    const float* __restrict__ lin_b,
    const float* __restrict__ sums,          // [0]=sum(g*lw) [1]=sum(be*lw)
    const int* __restrict__ src_lens,
    float* __restrict__ log_dur) {
    __shared__ __align__(16) unsigned char As[8192];
    __shared__ __align__(16) unsigned char Bs[66560];   // staging 64K / store buf 64x520 bf16
    __shared__ float red1[64][4], red2[64][4], red3[64][4];

    const int tid  = threadIdx.x;
    const int w    = tid >> 6;
    const int lane = tid & 63;
    const int lr   = lane & 15;      // MFMA row/col within 16
    const int lg   = lane >> 4;      // k-group 0..3
    const int b    = blockIdx.x >> 4;
    const int sb   = (blockIdx.x & 15) * 64;

    const unsigned short* Xblk = Xp + ((size_t)b * 1026 + sb) * 512;

    floatx4 acc[4][8];
#pragma unroll
    for (int mt = 0; mt < 4; ++mt)
#pragma unroll
        for (int nt = 0; nt < 8; ++nt) acc[mt][nt] = (floatx4){0.f, 0.f, 0.f, 0.f};

    for (int kk = 0; kk < 24; ++kk) {
        const int k  = kk >> 3;
        const int hc = (kk & 7) * 64;
        // ---- stage A (64x64) : 2 calls/wave ----
#pragma unroll
        for (int j2 = 0; j2 < 2; ++j2) {
            int rowbase = w * 16 + j2 * 8;
            int row = rowbase + (lane >> 3);
            int cg  = (lane & 7) ^ (row & 7);
            gld16(Xblk + (size_t)(row + k) * 512 + hc + cg * 8, As + rowbase * 128);
        }
        // ---- stage B (512x64 of Wt[k]) : 16 calls/wave ----
        const unsigned short* Wk = Wt + (size_t)k * 512 * 512;
#pragma unroll
        for (int j2 = 0; j2 < 16; ++j2) {
            int fbase = w * 128 + j2 * 8;
            int f  = fbase + (lane >> 3);
            int cg = (lane & 7) ^ (f & 7);
            gld16(Wk + (size_t)f * 512 + hc + cg * 8, Bs + fbase * 128);
        }
        __syncthreads();   // drains vmcnt -> staging visible
        // ---- 2 k-steps of K=32 ----
#pragma unroll
        for (int j = 0; j < 2; ++j) {
            const int xt = ((j * 4 + lg) ^ (lr & 7)) * 16;
            short8 af[4], bf[8];
#pragma unroll
            for (int mt = 0; mt < 4; ++mt)
                af[mt] = *(const short8*)(As + (mt * 16 + lr) * 128 + xt);
#pragma unroll
            for (int nt = 0; nt < 8; ++nt)
                bf[nt] = *(const short8*)(Bs + (w * 128 + nt * 16 + lr) * 128 + xt);
#pragma unroll
            for (int mt = 0; mt < 4; ++mt)
#pragma unroll
                for (int nt = 0; nt < 8; ++nt)
                    acc[mt][nt] = __builtin_amdgcn_mfma_f32_16x16x32_bf16(
                        af[mt], bf[nt], acc[mt][nt], 0, 0, 0);
        }
        __syncthreads();   // protect LDS before next staging overwrite
    }

    // ---- epilogue: bias + ReLU, per-row stats ----
    float bia[8], gam[8], bet[8], glw[8];
#pragma unroll
    for (int nt = 0; nt < 8; ++nt) {
        int f = w * 128 + nt * 16 + lr;
        bia[nt] = bias[f]; gam[nt] = gamma[f]; bet[nt] = beta[f];
        if (LOGDUR) glw[nt] = gam[nt] * lin_w[f];
    }
#pragma unroll
    for (int mt = 0; mt < 4; ++mt)
#pragma unroll
        for (int nt = 0; nt < 8; ++nt)
#pragma unroll
            for (int r = 0; r < 4; ++r)
                acc[mt][nt][r] = fmaxf(acc[mt][nt][r] + bia[nt], 0.f);

#pragma unroll
    for (int mt = 0; mt < 4; ++mt)
#pragma unroll
        for (int r = 0; r < 4; ++r) {
            float p1 = 0.f, p2 = 0.f, p3 = 0.f;
#pragma unroll
            for (int nt = 0; nt < 8; ++nt) {
                float v = acc[mt][nt][r];
                p1 += v; p2 += v * v;
                if (LOGDUR) p3 += v * glw[nt];
            }
#pragma unroll
            for (int m = 1; m < 16; m <<= 1) {
                p1 += __shfl_xor(p1, m, 64);
                p2 += __shfl_xor(p2, m, 64);
                if (LOGDUR) p3 += __shfl_xor(p3, m, 64);
            }
            if (lr == 0) {
                int row = mt * 16 + lg * 4 + r;
                red1[row][w] = p1; red2[row][w] = p2;
                if (LOGDUR) red3[row][w] = p3;
            }
        }
    __syncthreads();

    if constexpr (!LOGDUR) {
        float mu[4][4], rs[4][4];
#pragma unroll
        for (int mt = 0; mt < 4; ++mt)
#pragma unroll
            for (int r = 0; r < 4; ++r) {
                int row = mt * 16 + lg * 4 + r;
                float s1 = red1[row][0] + red1[row][1] + red1[row][2] + red1[row][3];
                float s2 = red2[row][0] + red2[row][1] + red2[row][2] + red2[row][3];
                float m  = s1 * (1.f / 512.f);
                float e  = s2 * (1.f / 512.f) - m * m;
                mu[mt][r] = m; rs[mt][r] = rsqrtf(e + 1e-5f);
            }
        // normalized bf16 -> LDS [64][520], then coalesced 16B copies out
#pragma unroll
        for (int mt = 0; mt < 4; ++mt)
#pragma unroll
            for (int nt = 0; nt < 8; ++nt)
#pragma unroll
                for (int r = 0; r < 4; ++r) {
                    int row = mt * 16 + lg * 4 + r;
                    float y = (acc[mt][nt][r] - mu[mt][r]) * rs[mt][r] * gam[nt] + bet[nt];
                    *(unsigned short*)(Bs + row * 1040 + (w * 128 + nt * 16 + lr) * 2) = f2b(y);
                }
        __syncthreads();
        unsigned short* Oblk = Op + ((size_t)b * 1026 + 1 + sb) * 512;
        for (int idx = tid; idx < 4096; idx += 256) {
            int row = idx >> 6, seg = idx & 63;
            uint4 v = *(const uint4*)(Bs + row * 1040 + seg * 16);
            *(uint4*)(Oblk + (size_t)row * 512 + seg * 8) = v;
        }
    } else {
        if (tid < 64) {
            int row = tid;
            float s1 = red1[row][0] + red1[row][1] + red1[row][2] + red1[row][3];
            float s2 = red2[row][0] + red2[row][1] + red2[row][2] + red2[row][3];
            float s3 = red3[row][0] + red3[row][1] + red3[row][2] + red3[row][3];
            float m  = s1 * (1.f / 512.f);
            float e  = s2 * (1.f / 512.f) - m * m;
            float rstd = rsqrtf(e + 1e-5f);
            float val  = rstd * (s3 - m * sums[0]) + sums[1] + lin_b[0];
            int s = sb + row;
            log_dur[b * S_ + s] = (s >= src_lens[b]) ? 0.f : val;
        }
    }
}

// ===================== scan / expand (unchanged) =====================

__global__ __launch_bounds__(256) void scan_kernel(
    const int* __restrict__ duration, const int* __restrict__ src_lens,
    int* __restrict__ csum, float* __restrict__ dur_out,
    float* __restrict__ tlen_out, float* __restrict__ tmask_out) {
    const int b = blockIdx.x, t = threadIdx.x;
    __shared__ int lds[256];
    __shared__ int total_sh;

    const int slen = src_lens[b];
    int loc[4];
    const int sb = t * 4;
#pragma unroll
    for (int i = 0; i < 4; ++i) {
        int s = sb + i;
        loc[i] = (s < slen) ? duration[b * S_ + s] : 0;
    }
    int tsum = loc[0] + loc[1] + loc[2] + loc[3];

    lds[t] = tsum;
    __syncthreads();
    for (int off = 1; off < 256; off <<= 1) {
        int v = (t >= off) ? lds[t - off] : 0;
        __syncthreads();
        lds[t] += v;
        __syncthreads();
    }
    int incl = lds[t];
    if (t == 255) total_sh = incl;

    int run = incl - tsum;
#pragma unroll
    for (int i = 0; i < 4; ++i) {
        run += loc[i];
        csum[b * S_ + sb + i]    = run;
        dur_out[b * S_ + sb + i] = (float)loc[i];
    }
    __syncthreads();
    const int total = total_sh;
    if (t == 0) tlen_out[b] = (float)total;
    for (int p = t; p < ML_; p += 256) tmask_out[b * ML_ + p] = (p >= total) ? 1.f : 0.f;
}

__global__ __launch_bounds__(256) void expand_kernel(
    const float* __restrict__ x, const int* __restrict__ csum,
    float* __restrict__ out) {
    const int tid  = threadIdx.x;
    const int row  = blockIdx.x * 2 + (tid >> 7);
    const int lane = tid & 127;
    const int b = row >> 12;
    const int p = row & (ML_ - 1);

    const int* cs = csum + b * S_;
    const int total = cs[S_ - 1];

    int lo = 0, hi = S_;
    while (lo < hi) {
        int mid = (lo + hi) >> 1;
        if (cs[mid] <= p) lo = mid + 1; else hi = mid;
    }
    int idx = lo < (S_ - 1) ? lo : (S_ - 1);

    float4 v = make_float4(0.f, 0.f, 0.f, 0.f);
    if (p < total) v = ((const float4*)x)[(size_t)(b * S_ + idx) * (H_ / 4) + lane];
    ((float4*)out)[(size_t)row * (H_ / 4) + lane] = v;
}

// ===================== launch =====================

extern "C" void kernel_launch(void* const* d_in, const int* in_sizes, int n_in,
                              void* d_out, int out_size, void* d_ws, size_t ws_size,
                              hipStream_t stream) {
    const float* x        = (const float*)d_in[0];
    const int*   duration = (const int*)d_in[1];
    const int*   src_lens = (const int*)d_in[2];
    const float* conv1_w = (const float*)d_in[4];
    const float* conv1_b = (const float*)d_in[5];
    const float* ln1_g   = (const float*)d_in[6];
    const float* ln1_b   = (const float*)d_in[7];
    const float* conv2_w = (const float*)d_in[8];
    const float* conv2_b = (const float*)d_in[9];
    const float* ln2_g   = (const float*)d_in[10];
    const float* ln2_b   = (const float*)d_in[11];
    const float* lin_w   = (const float*)d_in[12];
    const float* lin_b   = (const float*)d_in[13];

    float* out      = (float*)d_out;
    float* expanded = out;
    float* log_dur  = out + OFF_LOGDUR;
    float* dur_out  = out + OFF_DUR;
    float* tlen_out = out + OFF_TLEN;
    float* tmask    = out + OFF_TMASK;

    int*   csum = (int*)d_ws;                         // 128 KB
    float* sums = (float*)((char*)d_ws + 131072);     // 8 B

    unsigned short* Xp  = (unsigned short*)((char*)d_out + OFF_XP);
    unsigned short* H1p = (unsigned short*)((char*)d_out + OFF_H1P);
    unsigned short* Wt1 = (unsigned short*)((char*)d_out + OFF_WT1);
    unsigned short* Wt2 = (unsigned short*)((char*)d_out + OFF_WT2);

    cast_x_kernel<<<8192, 256, 0, stream>>>(x, Xp);
    zero_halos_kernel<<<64, 256, 0, stream>>>(Xp, H1p);
    transpose_w_kernel<<<dim3(16, 16, 3), 256, 0, stream>>>(conv1_w, Wt1);
    transpose_w_kernel<<<dim3(16, 16, 3), 256, 0, stream>>>(conv2_w, Wt2);
    sums_kernel<<<1, 64, 0, stream>>>(ln2_g, ln2_b, lin_w, sums);

    conv_mfma_kernel<false><<<512, 256, 0, stream>>>(
        Xp, Wt1, conv1_b, ln1_g, ln1_b, H1p,
        nullptr, nullptr, nullptr, nullptr, nullptr);
    conv_mfma_kernel<true><<<512, 256, 0, stream>>>(
        H1p, Wt2, conv2_b, ln2_g, ln2_b, nullptr,
        lin_w, lin_b, sums, src_lens, log_dur);

    scan_kernel<<<B_, 256, 0, stream>>>(duration, src_lens, csum, dur_out, tlen_out, tmask);
    expand_kernel<<<B_ * ML_ / 2, 256, 0, stream>>>(x, csum, expanded);
}

// Round 3
// 499.237 us; speedup vs baseline: 3.3869x; 1.0287x over previous
//
#include <hip/hip_runtime.h>
#include <hip/hip_bf16.h>

#define B_  32
#define S_  1024
#define H_  512      // == F
#define ML_ 4096

typedef short short8 __attribute__((ext_vector_type(8)));
typedef float floatx4 __attribute__((ext_vector_type(4)));

// ---- output layout (flat float32 view) ----
constexpr size_t OFF_LOGDUR = (size_t)B_ * ML_ * H_;        // 67108864
constexpr size_t OFF_DUR    = OFF_LOGDUR + (size_t)B_ * S_;
constexpr size_t OFF_TLEN   = OFF_DUR + (size_t)B_ * S_;
constexpr size_t OFF_TMASK  = OFF_TLEN + B_;

// ---- scratch staged inside d_out's expanded region (bytes) ----
constexpr size_t XP_BYTES = (size_t)B_ * 1026 * 512 * 2;    // 33,619,968
constexpr size_t WT_BYTES = (size_t)3 * 512 * 512 * 2;      // 1,572,864
constexpr size_t OFF_XP   = 0;
constexpr size_t OFF_H1P  = XP_BYTES;
constexpr size_t OFF_WT1  = 2 * XP_BYTES;
constexpr size_t OFF_WT2  = 2 * XP_BYTES + WT_BYTES;        // ends ~70.4 MB < 268 MB

// ---- d_ws layout (bytes) ----
constexpr size_t WS_CSUM = 0;                                // 32*1024*4 = 131072
constexpr size_t WS_SUMS = 131072;                           // 8 B
constexpr size_t WS_IDX  = 132096;                           // 32*4096*4 = 524288
constexpr size_t WS_NEED_IDX = WS_IDX + (size_t)B_ * ML_ * 4;

__device__ __forceinline__ float wave_red(float v) {
#pragma unroll
    for (int o = 32; o > 0; o >>= 1) v += __shfl_down(v, o, 64);
    return v;
}

__device__ __forceinline__ unsigned short f2b(float f) {
    __hip_bfloat16 h = __float2bfloat16(f);
    return *reinterpret_cast<unsigned short*>(&h);
}

__device__ __forceinline__ void gld16(const void* g, void* l) {
    __builtin_amdgcn_global_load_lds(
        (const __attribute__((address_space(1))) unsigned int*)g,
        (__attribute__((address_space(3))) unsigned int*)l, 16, 0, 0);
}

// ===================== prep kernels =====================

// blocks [0,8192): fp32 x -> bf16 Xp interior rows.
// blocks [8192,8224): zero halo rows of Xp and H1p.
__global__ __launch_bounds__(256) void cast_x_kernel(
    const float* __restrict__ x, unsigned short* __restrict__ Xp,
    unsigned short* __restrict__ H1p) {
    const int tid = threadIdx.x;
    if (blockIdx.x < 8192) {
        size_t gid = (size_t)blockIdx.x * 256 + tid;
        size_t i8  = gid * 8;
        int row = (int)(i8 >> 9);
        int col = (int)(i8 & 511);
        int b = row >> 10, s = row & 1023;
        float4 v0 = *(const float4*)(x + i8);
        float4 v1 = *(const float4*)(x + i8 + 4);
        unsigned short u[8];
        u[0] = f2b(v0.x); u[1] = f2b(v0.y); u[2] = f2b(v0.z); u[3] = f2b(v0.w);
        u[4] = f2b(v1.x); u[5] = f2b(v1.y); u[6] = f2b(v1.z); u[7] = f2b(v1.w);
        *(uint4*)(Xp + ((size_t)b * 1026 + 1 + s) * 512 + col) = *(const uint4*)u;
    } else {
        // 8192 uint4 halo slots: 128 rows x 64 segs (rows 0..63 Xp, 64..127 H1p)
        int slot = (blockIdx.x - 8192) * 256 + tid;
        int row  = slot >> 6, seg = slot & 63;
        unsigned short* p = (row >> 6) ? H1p : Xp;
        int rr = row & 63;
        int b = rr >> 1, r = (rr & 1) ? 1025 : 0;
        uint4 z; z.x = 0; z.y = 0; z.z = 0; z.w = 0;
        *(uint4*)(p + ((size_t)(b * 1026 + r)) * 512 + seg * 8) = z;
    }
}

// W[k][h][f] fp32 -> Wt[k][f][h] bf16; z in [0,6): both weight tensors
__global__ __launch_bounds__(256) void transpose_w_kernel(
    const float* __restrict__ W1, const float* __restrict__ W2,
    unsigned short* __restrict__ Wt1, unsigned short* __restrict__ Wt2) {
    __shared__ float t[32][33];
    int z = blockIdx.z;
    const float* W = (z < 3) ? W1 : W2;
    unsigned short* Wt = (z < 3) ? Wt1 : Wt2;
    int k  = (z < 3) ? z : z - 3;
    int h0 = blockIdx.x * 32, f0 = blockIdx.y * 32;
    int tx = threadIdx.x & 31, ty = threadIdx.x >> 5;
    const float* Wk = W + (size_t)k * 512 * 512;
    unsigned short* Wtk = Wt + (size_t)k * 512 * 512;
#pragma unroll
    for (int i = 0; i < 4; ++i)
        t[ty + 8 * i][tx] = Wk[(size_t)(h0 + ty + 8 * i) * 512 + f0 + tx];
    __syncthreads();
#pragma unroll
    for (int i = 0; i < 4; ++i)
        Wtk[(size_t)(f0 + ty + 8 * i) * 512 + h0 + tx] = f2b(t[tx][ty + 8 * i]);
}

__global__ __launch_bounds__(64) void sums_kernel(
    const float* __restrict__ g, const float* __restrict__ be,
    const float* __restrict__ lw, float* __restrict__ out) {
    int t = threadIdx.x;
    float a = 0.f, c = 0.f;
    for (int f = t; f < 512; f += 64) { a += g[f] * lw[f]; c += be[f] * lw[f]; }
    a = wave_red(a); c = wave_red(c);
    if (t == 0) { out[0] = a; out[1] = c; }
}

// ===================== fused conv+bias+ReLU+LN (bf16 MFMA) =====================
// Block: 512 threads (8 waves), tile M=128 (s-rows) x N=512 (all f).
// Wave: M=128 (8 mt) x N=64 (4 nt). K-loop: 24 iters (3 taps x 8 hc-chunks of 64).
// Grid 256 = 1 block/CU.
template <bool LOGDUR>
__global__ __launch_bounds__(512, 2) void conv_mfma_kernel(
    const unsigned short* __restrict__ Xp,   // [B][1026][512] padded bf16
    const unsigned short* __restrict__ Wt,   // [3][512][512] f-major bf16
    const float* __restrict__ bias,
    const float* __restrict__ gamma,
    const float* __restrict__ beta,
    unsigned short* __restrict__ Op,         // conv1: padded bf16 out
    const float* __restrict__ lin_w,
    const float* __restrict__ lin_b,
    const float* __restrict__ sums,          // [0]=sum(g*lw) [1]=sum(be*lw)
    const int* __restrict__ src_lens,
    float* __restrict__ log_dur) {
    __shared__ __align__(16) unsigned char As[16384];   // 128 rows x 128 B
    __shared__ __align__(16) unsigned char Bs[66560];   // staging 64K / store buf 64x1040
    __shared__ float red1[128][8], red2[128][8], red3[128][8];

    const int tid  = threadIdx.x;
    const int w    = tid >> 6;
    const int lane = tid & 63;
    const int lr   = lane & 15;
    const int lg   = lane >> 4;
    const int b    = blockIdx.x >> 3;
    const int sb   = (blockIdx.x & 7) * 128;

    const unsigned short* Xblk = Xp + ((size_t)b * 1026 + sb) * 512;

    floatx4 acc[8][4];
#pragma unroll
    for (int mt = 0; mt < 8; ++mt)
#pragma unroll
        for (int nt = 0; nt < 4; ++nt) acc[mt][nt] = (floatx4){0.f, 0.f, 0.f, 0.f};

    for (int kk = 0; kk < 24; ++kk) {
        const int k  = kk >> 3;
        const int hc = (kk & 7) * 64;
        // ---- stage A (128x64) : 2 calls/wave ----
#pragma unroll
        for (int j2 = 0; j2 < 2; ++j2) {
            int rowbase = w * 16 + j2 * 8;
            int row = rowbase + (lane >> 3);
            int cg  = (lane & 7) ^ (row & 7);
            gld16(Xblk + (size_t)(row + k) * 512 + hc + cg * 8, As + rowbase * 128);
        }
        // ---- stage B (512x64 of Wt[k]) : 8 calls/wave ----
        const unsigned short* Wk = Wt + (size_t)k * 512 * 512;
#pragma unroll
        for (int j2 = 0; j2 < 8; ++j2) {
            int fbase = w * 64 + j2 * 8;
            int f  = fbase + (lane >> 3);
            int cg = (lane & 7) ^ (f & 7);
            gld16(Wk + (size_t)f * 512 + hc + cg * 8, Bs + fbase * 128);
        }
        __syncthreads();
#pragma unroll
        for (int j = 0; j < 2; ++j) {
            const int xt = ((j * 4 + lg) ^ (lr & 7)) * 16;
            short8 af[8], bf[4];
#pragma unroll
            for (int mt = 0; mt < 8; ++mt)
                af[mt] = *(const short8*)(As + (mt * 16 + lr) * 128 + xt);
#pragma unroll
            for (int nt = 0; nt < 4; ++nt)
                bf[nt] = *(const short8*)(Bs + (w * 64 + nt * 16 + lr) * 128 + xt);
#pragma unroll
            for (int mt = 0; mt < 8; ++mt)
#pragma unroll
                for (int nt = 0; nt < 4; ++nt)
                    acc[mt][nt] = __builtin_amdgcn_mfma_f32_16x16x32_bf16(
                        af[mt], bf[nt], acc[mt][nt], 0, 0, 0);
        }
        __syncthreads();
    }

    // ---- epilogue: bias + ReLU, per-row stats ----
    float bia[4], gam[4], bet[4], glw[4];
#pragma unroll
    for (int nt = 0; nt < 4; ++nt) {
        int f = w * 64 + nt * 16 + lr;
        bia[nt] = bias[f]; gam[nt] = gamma[f]; bet[nt] = beta[f];
        if (LOGDUR) glw[nt] = gam[nt] * lin_w[f];
    }
#pragma unroll
    for (int mt = 0; mt < 8; ++mt)
#pragma unroll
        for (int nt = 0; nt < 4; ++nt)
#pragma unroll
            for (int r = 0; r < 4; ++r)
                acc[mt][nt][r] = fmaxf(acc[mt][nt][r] + bia[nt], 0.f);

#pragma unroll
    for (int mt = 0; mt < 8; ++mt)
#pragma unroll
        for (int r = 0; r < 4; ++r) {
            float p1 = 0.f, p2 = 0.f, p3 = 0.f;
#pragma unroll
            for (int nt = 0; nt < 4; ++nt) {
                float v = acc[mt][nt][r];
                p1 += v; p2 += v * v;
                if (LOGDUR) p3 += v * glw[nt];
            }
#pragma unroll
            for (int m = 1; m < 16; m <<= 1) {
                p1 += __shfl_xor(p1, m, 64);
                p2 += __shfl_xor(p2, m, 64);
                if (LOGDUR) p3 += __shfl_xor(p3, m, 64);
            }
            if (lr == 0) {
                int row = mt * 16 + lg * 4 + r;
                red1[row][w] = p1; red2[row][w] = p2;
                if (LOGDUR) red3[row][w] = p3;
            }
        }
    __syncthreads();

    if constexpr (!LOGDUR) {
        unsigned short* Oblk = Op + ((size_t)b * 1026 + 1 + sb) * 512;
#pragma unroll
        for (int half = 0; half < 2; ++half) {
#pragma unroll
            for (int mi = 0; mi < 4; ++mi) {
                int mt = half * 4 + mi;
#pragma unroll
                for (int r = 0; r < 4; ++r) {
                    int row = mt * 16 + lg * 4 + r;
                    float s1 = 0.f, s2 = 0.f;
#pragma unroll
                    for (int ww = 0; ww < 8; ++ww) { s1 += red1[row][ww]; s2 += red2[row][ww]; }
                    float mu = s1 * (1.f / 512.f);
                    float rstd = rsqrtf(s2 * (1.f / 512.f) - mu * mu + 1e-5f);
#pragma unroll
                    for (int nt = 0; nt < 4; ++nt) {
                        float y = (acc[mt][nt][r] - mu) * rstd * gam[nt] + bet[nt];
                        ((unsigned short*)Bs)[(row - half * 64) * 520 + w * 64 + nt * 16 + lr] = f2b(y);
                    }
                }
            }
            __syncthreads();
            for (int it = tid; it < 4096; it += 512) {
                int rr = it >> 6, seg = it & 63;
                uint4 v = *(const uint4*)(Bs + rr * 1040 + seg * 16);
                *(uint4*)(Oblk + (size_t)(half * 64 + rr) * 512 + seg * 8) = v;
            }
            __syncthreads();
        }
    } else {
        if (tid < 128) {
            int row = tid;
            float s1 = 0.f, s2 = 0.f, s3 = 0.f;
#pragma unroll
            for (int ww = 0; ww < 8; ++ww) {
                s1 += red1[row][ww]; s2 += red2[row][ww]; s3 += red3[row][ww];
            }
            float mu   = s1 * (1.f / 512.f);
            float rstd = rsqrtf(s2 * (1.f / 512.f) - mu * mu + 1e-5f);
            float val  = rstd * (s3 - mu * sums[0]) + sums[1] + lin_b[0];
            int s = sb + row;
            log_dur[b * S_ + s] = (s >= src_lens[b]) ? 0.f : val;
        }
    }
}

// ===================== scan (+ idx scatter) =====================

__global__ __launch_bounds__(256) void scan_kernel(
    const int* __restrict__ duration, const int* __restrict__ src_lens,
    int* __restrict__ csum, int* __restrict__ idx, int do_idx,
    float* __restrict__ dur_out, float* __restrict__ tlen_out,
    float* __restrict__ tmask_out) {
    const int b = blockIdx.x, t = threadIdx.x;
    __shared__ int lds[256];
    __shared__ int total_sh;

    const int slen = src_lens[b];
    int loc[4];
    const int sb = t * 4;
#pragma unroll
    for (int i = 0; i < 4; ++i) {
        int s = sb + i;
        loc[i] = (s < slen) ? duration[b * S_ + s] : 0;
    }
    int tsum = loc[0] + loc[1] + loc[2] + loc[3];

    lds[t] = tsum;
    __syncthreads();
    for (int off = 1; off < 256; off <<= 1) {
        int v = (t >= off) ? lds[t - off] : 0;
        __syncthreads();
        lds[t] += v;
        __syncthreads();
    }
    int incl = lds[t];
    if (t == 255) total_sh = incl;

    int run = incl - tsum;
#pragma unroll
    for (int i = 0; i < 4; ++i) {
        int start = run;
        run += loc[i];
        csum[b * S_ + sb + i]    = run;
        dur_out[b * S_ + sb + i] = (float)loc[i];
        if (do_idx)
            for (int q = start; q < run; ++q) idx[b * ML_ + q] = sb + i;
    }
    __syncthreads();
    const int total = total_sh;
    if (t == 0) tlen_out[b] = (float)total;
    for (int p = t; p < ML_; p += 256) tmask_out[b * ML_ + p] = (p >= total) ? 1.f : 0.f;
}

// ===================== expand =====================

// fast path: precomputed idx
__global__ __launch_bounds__(256) void expand_idx_kernel(
    const float* __restrict__ x, const int* __restrict__ csum,
    const int* __restrict__ idx, float* __restrict__ out) {
    const int tid  = threadIdx.x;
    const int row  = blockIdx.x * 2 + (tid >> 7);
    const int lane = tid & 127;
    const int b = row >> 12;
    const int p = row & (ML_ - 1);
    const int total = csum[b * S_ + S_ - 1];
    float4 v = make_float4(0.f, 0.f, 0.f, 0.f);
    if (p < total) {
        int ir = idx[b * ML_ + p];
        v = ((const float4*)x)[(size_t)(b * S_ + ir) * (H_ / 4) + lane];
    }
    ((float4*)out)[(size_t)row * (H_ / 4) + lane] = v;
}

// fallback: in-kernel binary search
__global__ __launch_bounds__(256) void expand_kernel(
    const float* __restrict__ x, const int* __restrict__ csum,
    float* __restrict__ out) {
    const int tid  = threadIdx.x;
    const int row  = blockIdx.x * 2 + (tid >> 7);
    const int lane = tid & 127;
    const int b = row >> 12;
    const int p = row & (ML_ - 1);
    const int* cs = csum + b * S_;
    const int total = cs[S_ - 1];
    int lo = 0, hi = S_;
    while (lo < hi) {
        int mid = (lo + hi) >> 1;
        if (cs[mid] <= p) lo = mid + 1; else hi = mid;
    }
    int ir = lo < (S_ - 1) ? lo : (S_ - 1);
    float4 v = make_float4(0.f, 0.f, 0.f, 0.f);
    if (p < total) v = ((const float4*)x)[(size_t)(b * S_ + ir) * (H_ / 4) + lane];
    ((float4*)out)[(size_t)row * (H_ / 4) + lane] = v;
}

// ===================== launch =====================

extern "C" void kernel_launch(void* const* d_in, const int* in_sizes, int n_in,
                              void* d_out, int out_size, void* d_ws, size_t ws_size,
                              hipStream_t stream) {
    const float* x        = (const float*)d_in[0];
    const int*   duration = (const int*)d_in[1];
    const int*   src_lens = (const int*)d_in[2];
    const float* conv1_w = (const float*)d_in[4];
    const float* conv1_b = (const float*)d_in[5];
    const float* ln1_g   = (const float*)d_in[6];
    const float* ln1_b   = (const float*)d_in[7];
    const float* conv2_w = (const float*)d_in[8];
    const float* conv2_b = (const float*)d_in[9];
    const float* ln2_g   = (const float*)d_in[10];
    const float* ln2_b   = (const float*)d_in[11];
    const float* lin_w   = (const float*)d_in[12];
    const float* lin_b   = (const float*)d_in[13];

    float* out      = (float*)d_out;
    float* expanded = out;
    float* log_dur  = out + OFF_LOGDUR;
    float* dur_out  = out + OFF_DUR;
    float* tlen_out = out + OFF_TLEN;
    float* tmask    = out + OFF_TMASK;

    int*   csum = (int*)((char*)d_ws + WS_CSUM);
    float* sums = (float*)((char*)d_ws + WS_SUMS);
    int*   idx  = (int*)((char*)d_ws + WS_IDX);
    const int use_idx = (ws_size >= WS_NEED_IDX) ? 1 : 0;

    unsigned short* Xp  = (unsigned short*)((char*)d_out + OFF_XP);
    unsigned short* H1p = (unsigned short*)((char*)d_out + OFF_H1P);
    unsigned short* Wt1 = (unsigned short*)((char*)d_out + OFF_WT1);
    unsigned short* Wt2 = (unsigned short*)((char*)d_out + OFF_WT2);

    cast_x_kernel<<<8224, 256, 0, stream>>>(x, Xp, H1p);
    transpose_w_kernel<<<dim3(16, 16, 6), 256, 0, stream>>>(conv1_w, conv2_w, Wt1, Wt2);
    sums_kernel<<<1, 64, 0, stream>>>(ln2_g, ln2_b, lin_w, sums);

    conv_mfma_kernel<false><<<256, 512, 0, stream>>>(
        Xp, Wt1, conv1_b, ln1_g, ln1_b, H1p,
        nullptr, nullptr, nullptr, nullptr, nullptr);
    conv_mfma_kernel<true><<<256, 512, 0, stream>>>(
        H1p, Wt2, conv2_b, ln2_g, ln2_b, nullptr,
        lin_w, lin_b, sums, src_lens, log_dur);

    scan_kernel<<<B_, 256, 0, stream>>>(duration, src_lens, csum, idx, use_idx,
                                        dur_out, tlen_out, tmask);
    if (use_idx)
        expand_idx_kernel<<<B_ * ML_ / 2, 256, 0, stream>>>(x, csum, idx, expanded);
    else
        expand_kernel<<<B_ * ML_ / 2, 256, 0, stream>>>(x, csum, expanded);
}

// Round 4
// 498.106 us; speedup vs baseline: 3.3946x; 1.0023x over previous
//
#include <hip/hip_runtime.h>
#include <hip/hip_bf16.h>

#define B_  32
#define S_  1024
#define H_  512      // == F
#define ML_ 4096

typedef short short8 __attribute__((ext_vector_type(8)));
typedef float floatx4 __attribute__((ext_vector_type(4)));

// ---- output layout (flat float32 view) ----
constexpr size_t OFF_LOGDUR = (size_t)B_ * ML_ * H_;        // 67108864
constexpr size_t OFF_DUR    = OFF_LOGDUR + (size_t)B_ * S_;
constexpr size_t OFF_TLEN   = OFF_DUR + (size_t)B_ * S_;
constexpr size_t OFF_TMASK  = OFF_TLEN + B_;

// ---- scratch staged inside d_out's expanded region (bytes) ----
constexpr size_t XP_BYTES = (size_t)B_ * 1026 * 512 * 2;    // 33,619,968
constexpr size_t WT_BYTES = (size_t)3 * 512 * 512 * 2;      // 1,572,864
constexpr size_t OFF_XP   = 0;
constexpr size_t OFF_H1P  = XP_BYTES;
constexpr size_t OFF_WT1  = 2 * XP_BYTES;
constexpr size_t OFF_WT2  = 2 * XP_BYTES + WT_BYTES;        // ends ~70.4 MB < 268 MB

// ---- d_ws layout (bytes) ----
constexpr size_t WS_CSUM = 0;                                // 32*1024*4 = 131072
constexpr size_t WS_SUMS = 131072;                           // 8 B
constexpr size_t WS_IDX  = 132096;                           // 32*4096*4 = 524288
constexpr size_t WS_NEED_IDX = WS_IDX + (size_t)B_ * ML_ * 4;

__device__ __forceinline__ float wave_red(float v) {
#pragma unroll
    for (int o = 32; o > 0; o >>= 1) v += __shfl_down(v, o, 64);
    return v;
}

__device__ __forceinline__ unsigned short f2b(float f) {
    __hip_bfloat16 h = __float2bfloat16(f);
    return *reinterpret_cast<unsigned short*>(&h);
}

__device__ __forceinline__ void gld16(const void* g, void* l) {
    __builtin_amdgcn_global_load_lds(
        (const __attribute__((address_space(1))) unsigned int*)g,
        (__attribute__((address_space(3))) unsigned int*)l, 16, 0, 0);
}

// ===================== prep kernels =====================

// blocks [0,8192): fp32 x -> bf16 Xp interior rows.
// blocks [8192,8224): zero halo rows of Xp and H1p.
__global__ __launch_bounds__(256) void cast_x_kernel(
    const float* __restrict__ x, unsigned short* __restrict__ Xp,
    unsigned short* __restrict__ H1p) {
    const int tid = threadIdx.x;
    if (blockIdx.x < 8192) {
        size_t gid = (size_t)blockIdx.x * 256 + tid;
        size_t i8  = gid * 8;
        int row = (int)(i8 >> 9);
        int col = (int)(i8 & 511);
        int b = row >> 10, s = row & 1023;
        float4 v0 = *(const float4*)(x + i8);
        float4 v1 = *(const float4*)(x + i8 + 4);
        unsigned short u[8];
        u[0] = f2b(v0.x); u[1] = f2b(v0.y); u[2] = f2b(v0.z); u[3] = f2b(v0.w);
        u[4] = f2b(v1.x); u[5] = f2b(v1.y); u[6] = f2b(v1.z); u[7] = f2b(v1.w);
        *(uint4*)(Xp + ((size_t)b * 1026 + 1 + s) * 512 + col) = *(const uint4*)u;
    } else {
        int slot = (blockIdx.x - 8192) * 256 + tid;
        int row  = slot >> 6, seg = slot & 63;
        unsigned short* p = (row >> 6) ? H1p : Xp;
        int rr = row & 63;
        int b = rr >> 1, r = (rr & 1) ? 1025 : 0;
        uint4 z; z.x = 0; z.y = 0; z.z = 0; z.w = 0;
        *(uint4*)(p + ((size_t)(b * 1026 + r)) * 512 + seg * 8) = z;
    }
}

// W[k][h][f] fp32 -> Wt[k][f][h] bf16; z in [0,6): both weight tensors
__global__ __launch_bounds__(256) void transpose_w_kernel(
    const float* __restrict__ W1, const float* __restrict__ W2,
    unsigned short* __restrict__ Wt1, unsigned short* __restrict__ Wt2) {
    __shared__ float t[32][33];
    int z = blockIdx.z;
    const float* W = (z < 3) ? W1 : W2;
    unsigned short* Wt = (z < 3) ? Wt1 : Wt2;
    int k  = (z < 3) ? z : z - 3;
    int h0 = blockIdx.x * 32, f0 = blockIdx.y * 32;
    int tx = threadIdx.x & 31, ty = threadIdx.x >> 5;
    const float* Wk = W + (size_t)k * 512 * 512;
    unsigned short* Wtk = Wt + (size_t)k * 512 * 512;
#pragma unroll
    for (int i = 0; i < 4; ++i)
        t[ty + 8 * i][tx] = Wk[(size_t)(h0 + ty + 8 * i) * 512 + f0 + tx];
    __syncthreads();
#pragma unroll
    for (int i = 0; i < 4; ++i)
        Wtk[(size_t)(f0 + ty + 8 * i) * 512 + h0 + tx] = f2b(t[tx][ty + 8 * i]);
}

__global__ __launch_bounds__(64) void sums_kernel(
    const float* __restrict__ g, const float* __restrict__ be,
    const float* __restrict__ lw, float* __restrict__ out) {
    int t = threadIdx.x;
    float a = 0.f, c = 0.f;
    for (int f = t; f < 512; f += 64) { a += g[f] * lw[f]; c += be[f] * lw[f]; }
    a = wave_red(a); c = wave_red(c);
    if (t == 0) { out[0] = a; out[1] = c; }
}

// ===================== fused conv+bias+ReLU+LN (bf16 MFMA) =====================
// Block: 512 threads (8 waves), tile M=128 x N=512. Grid 256 = 1 block/CU.
// K-loop phase-skewed per block: blocks on the same XCD walk DIFFERENT weight
// chunks at any instant -> L2 slices all active (fixes same-line hotspot).
template <bool LOGDUR>
__global__ __launch_bounds__(512, 2) void conv_mfma_kernel(
    const unsigned short* __restrict__ Xp,   // [B][1026][512] padded bf16
    const unsigned short* __restrict__ Wt,   // [3][512][512] f-major bf16
    const float* __restrict__ bias,
    const float* __restrict__ gamma,
    const float* __restrict__ beta,
    unsigned short* __restrict__ Op,         // conv1: padded bf16 out
    const float* __restrict__ lin_w,
    const float* __restrict__ lin_b,
    const float* __restrict__ sums,          // [0]=sum(g*lw) [1]=sum(be*lw)
    const int* __restrict__ src_lens,
    float* __restrict__ log_dur) {
    __shared__ __align__(16) unsigned char As[16384];   // 128 rows x 128 B
    __shared__ __align__(16) unsigned char Bs[66560];   // staging 64K / store buf 64x1040
    __shared__ float red1[128][8], red2[128][8], red3[128][8];

    const int tid  = threadIdx.x;
    const int w    = tid >> 6;
    const int lane = tid & 63;
    const int lr   = lane & 15;
    const int lg   = lane >> 4;
    const int b    = blockIdx.x >> 3;
    const int sb   = (blockIdx.x & 7) * 128;

    // phase: blocks round-robin to XCDs by blockIdx%8 -> use blockIdx/8 so
    // co-XCD blocks get distinct phases (32 blocks/XCD covers all 24 phases)
    const int phase = (blockIdx.x >> 3) % 24;

    const unsigned short* Xblk = Xp + ((size_t)b * 1026 + sb) * 512;

    floatx4 acc[8][4];
#pragma unroll
    for (int mt = 0; mt < 8; ++mt)
#pragma unroll
        for (int nt = 0; nt < 4; ++nt) acc[mt][nt] = (floatx4){0.f, 0.f, 0.f, 0.f};

    for (int kk0 = 0; kk0 < 24; ++kk0) {
        int kk = kk0 + phase; if (kk >= 24) kk -= 24;
        const int k  = kk >> 3;
        const int hc = (kk & 7) * 64;
        // ---- stage A (128x64) : 2 calls/wave ----
#pragma unroll
        for (int j2 = 0; j2 < 2; ++j2) {
            int rowbase = w * 16 + j2 * 8;
            int row = rowbase + (lane >> 3);
            int cg  = (lane & 7) ^ (row & 7);
            gld16(Xblk + (size_t)(row + k) * 512 + hc + cg * 8, As + rowbase * 128);
        }
        // ---- stage B (512x64 of Wt[k]) : 8 calls/wave ----
        const unsigned short* Wk = Wt + (size_t)k * 512 * 512;
#pragma unroll
        for (int j2 = 0; j2 < 8; ++j2) {
            int fbase = w * 64 + j2 * 8;
            int f  = fbase + (lane >> 3);
            int cg = (lane & 7) ^ (f & 7);
            gld16(Wk + (size_t)f * 512 + hc + cg * 8, Bs + fbase * 128);
        }
        __syncthreads();
#pragma unroll
        for (int j = 0; j < 2; ++j) {
            const int xt = ((j * 4 + lg) ^ (lr & 7)) * 16;
            short8 af[8], bf[4];
#pragma unroll
            for (int mt = 0; mt < 8; ++mt)
                af[mt] = *(const short8*)(As + (mt * 16 + lr) * 128 + xt);
#pragma unroll
            for (int nt = 0; nt < 4; ++nt)
                bf[nt] = *(const short8*)(Bs + (w * 64 + nt * 16 + lr) * 128 + xt);
#pragma unroll
            for (int mt = 0; mt < 8; ++mt)
#pragma unroll
                for (int nt = 0; nt < 4; ++nt)
                    acc[mt][nt] = __builtin_amdgcn_mfma_f32_16x16x32_bf16(
                        af[mt], bf[nt], acc[mt][nt], 0, 0, 0);
        }
        __syncthreads();
    }

    // ---- epilogue: bias + ReLU, per-row stats ----
    float bia[4], gam[4], bet[4], glw[4];
#pragma unroll
    for (int nt = 0; nt < 4; ++nt) {
        int f = w * 64 + nt * 16 + lr;
        bia[nt] = bias[f]; gam[nt] = gamma[f]; bet[nt] = beta[f];
        if (LOGDUR) glw[nt] = gam[nt] * lin_w[f];
    }
#pragma unroll
    for (int mt = 0; mt < 8; ++mt)
#pragma unroll
        for (int nt = 0; nt < 4; ++nt)
#pragma unroll
            for (int r = 0; r < 4; ++r)
                acc[mt][nt][r] = fmaxf(acc[mt][nt][r] + bia[nt], 0.f);

#pragma unroll
    for (int mt = 0; mt < 8; ++mt)
#pragma unroll
        for (int r = 0; r < 4; ++r) {
            float p1 = 0.f, p2 = 0.f, p3 = 0.f;
#pragma unroll
            for (int nt = 0; nt < 4; ++nt) {
                float v = acc[mt][nt][r];
                p1 += v; p2 += v * v;
                if (LOGDUR) p3 += v * glw[nt];
            }
#pragma unroll
            for (int m = 1; m < 16; m <<= 1) {
                p1 += __shfl_xor(p1, m, 64);
                p2 += __shfl_xor(p2, m, 64);
                if (LOGDUR) p3 += __shfl_xor(p3, m, 64);
            }
            if (lr == 0) {
                int row = mt * 16 + lg * 4 + r;
                red1[row][w] = p1; red2[row][w] = p2;
                if (LOGDUR) red3[row][w] = p3;
            }
        }
    __syncthreads();

    if constexpr (!LOGDUR) {
        unsigned short* Oblk = Op + ((size_t)b * 1026 + 1 + sb) * 512;
#pragma unroll
        for (int half = 0; half < 2; ++half) {
#pragma unroll
            for (int mi = 0; mi < 4; ++mi) {
                int mt = half * 4 + mi;
#pragma unroll
                for (int r = 0; r < 4; ++r) {
                    int row = mt * 16 + lg * 4 + r;
                    float s1 = 0.f, s2 = 0.f;
#pragma unroll
                    for (int ww = 0; ww < 8; ++ww) { s1 += red1[row][ww]; s2 += red2[row][ww]; }
                    float mu = s1 * (1.f / 512.f);
                    float rstd = rsqrtf(s2 * (1.f / 512.f) - mu * mu + 1e-5f);
#pragma unroll
                    for (int nt = 0; nt < 4; ++nt) {
                        float y = (acc[mt][nt][r] - mu) * rstd * gam[nt] + bet[nt];
                        ((unsigned short*)Bs)[(row - half * 64) * 520 + w * 64 + nt * 16 + lr] = f2b(y);
                    }
                }
            }
            __syncthreads();
            for (int it = tid; it < 4096; it += 512) {
                int rr = it >> 6, seg = it & 63;
                uint4 v = *(const uint4*)(Bs + rr * 1040 + seg * 16);
                *(uint4*)(Oblk + (size_t)(half * 64 + rr) * 512 + seg * 8) = v;
            }
            __syncthreads();
        }
    } else {
        if (tid < 128) {
            int row = tid;
            float s1 = 0.f, s2 = 0.f, s3 = 0.f;
#pragma unroll
            for (int ww = 0; ww < 8; ++ww) {
                s1 += red1[row][ww]; s2 += red2[row][ww]; s3 += red3[row][ww];
            }
            float mu   = s1 * (1.f / 512.f);
            float rstd = rsqrtf(s2 * (1.f / 512.f) - mu * mu + 1e-5f);
            float val  = rstd * (s3 - mu * sums[0]) + sums[1] + lin_b[0];
            int s = sb + row;
            log_dur[b * S_ + s] = (s >= src_lens[b]) ? 0.f : val;
        }
    }
}

// ===================== scan (+ idx scatter) =====================

__global__ __launch_bounds__(256) void scan_kernel(
    const int* __restrict__ duration, const int* __restrict__ src_lens,
    int* __restrict__ csum, int* __restrict__ idx, int do_idx,
    float* __restrict__ dur_out, float* __restrict__ tlen_out,
    float* __restrict__ tmask_out) {
    const int b = blockIdx.x, t = threadIdx.x;
    __shared__ int lds[256];
    __shared__ int total_sh;

    const int slen = src_lens[b];
    int loc[4];
    const int sb = t * 4;
#pragma unroll
    for (int i = 0; i < 4; ++i) {
        int s = sb + i;
        loc[i] = (s < slen) ? duration[b * S_ + s] : 0;
    }
    int tsum = loc[0] + loc[1] + loc[2] + loc[3];

    lds[t] = tsum;
    __syncthreads();
    for (int off = 1; off < 256; off <<= 1) {
        int v = (t >= off) ? lds[t - off] : 0;
        __syncthreads();
        lds[t] += v;
        __syncthreads();
    }
    int incl = lds[t];
    if (t == 255) total_sh = incl;

    int run = incl - tsum;
#pragma unroll
    for (int i = 0; i < 4; ++i) {
        int start = run;
        run += loc[i];
        csum[b * S_ + sb + i]    = run;
        dur_out[b * S_ + sb + i] = (float)loc[i];
        if (do_idx)
            for (int q = start; q < run; ++q) idx[b * ML_ + q] = sb + i;
    }
    __syncthreads();
    const int total = total_sh;
    if (t == 0) tlen_out[b] = (float)total;
    for (int p = t; p < ML_; p += 256) tmask_out[b * ML_ + p] = (p >= total) ? 1.f : 0.f;
}

// ===================== expand =====================

__global__ __launch_bounds__(256) void expand_idx_kernel(
    const float* __restrict__ x, const int* __restrict__ csum,
    const int* __restrict__ idx, float* __restrict__ out) {
    const int tid  = threadIdx.x;
    const int row  = blockIdx.x * 2 + (tid >> 7);
    const int lane = tid & 127;
    const int b = row >> 12;
    const int p = row & (ML_ - 1);
    const int total = csum[b * S_ + S_ - 1];
    float4 v = make_float4(0.f, 0.f, 0.f, 0.f);
    if (p < total) {
        int ir = idx[b * ML_ + p];
        v = ((const float4*)x)[(size_t)(b * S_ + ir) * (H_ / 4) + lane];
    }
    ((float4*)out)[(size_t)row * (H_ / 4) + lane] = v;
}

__global__ __launch_bounds__(256) void expand_kernel(
    const float* __restrict__ x, const int* __restrict__ csum,
    float* __restrict__ out) {
    const int tid  = threadIdx.x;
    const int row  = blockIdx.x * 2 + (tid >> 7);
    const int lane = tid & 127;
    const int b = row >> 12;
    const int p = row & (ML_ - 1);
    const int* cs = csum + b * S_;
    const int total = cs[S_ - 1];
    int lo = 0, hi = S_;
    while (lo < hi) {
        int mid = (lo + hi) >> 1;
        if (cs[mid] <= p) lo = mid + 1; else hi = mid;
    }
    int ir = lo < (S_ - 1) ? lo : (S_ - 1);
    float4 v = make_float4(0.f, 0.f, 0.f, 0.f);
    if (p < total) v = ((const float4*)x)[(size_t)(b * S_ + ir) * (H_ / 4) + lane];
    ((float4*)out)[(size_t)row * (H_ / 4) + lane] = v;
}

// ===================== launch =====================

extern "C" void kernel_launch(void* const* d_in, const int* in_sizes, int n_in,
                              void* d_out, int out_size, void* d_ws, size_t ws_size,
                              hipStream_t stream) {
    const float* x        = (const float*)d_in[0];
    const int*   duration = (const int*)d_in[1];
    const int*   src_lens = (const int*)d_in[2];
    const float* conv1_w = (const float*)d_in[4];
    const float* conv1_b = (const float*)d_in[5];
    const float* ln1_g   = (const float*)d_in[6];
    const float* ln1_b   = (const float*)d_in[7];
    const float* conv2_w = (const float*)d_in[8];
    const float* conv2_b = (const float*)d_in[9];
    const float* ln2_g   = (const float*)d_in[10];
    const float* ln2_b   = (const float*)d_in[11];
    const float* lin_w   = (const float*)d_in[12];
    const float* lin_b   = (const float*)d_in[13];

    float* out      = (float*)d_out;
    float* expanded = out;
    float* log_dur  = out + OFF_LOGDUR;
    float* dur_out  = out + OFF_DUR;
    float* tlen_out = out + OFF_TLEN;
    float* tmask    = out + OFF_TMASK;

    int*   csum = (int*)((char*)d_ws + WS_CSUM);
    float* sums = (float*)((char*)d_ws + WS_SUMS);
    int*   idx  = (int*)((char*)d_ws + WS_IDX);
    const int use_idx = (ws_size >= WS_NEED_IDX) ? 1 : 0;

    unsigned short* Xp  = (unsigned short*)((char*)d_out + OFF_XP);
    unsigned short* H1p = (unsigned short*)((char*)d_out + OFF_H1P);
    unsigned short* Wt1 = (unsigned short*)((char*)d_out + OFF_WT1);
    unsigned short* Wt2 = (unsigned short*)((char*)d_out + OFF_WT2);

    cast_x_kernel<<<8224, 256, 0, stream>>>(x, Xp, H1p);
    transpose_w_kernel<<<dim3(16, 16, 6), 256, 0, stream>>>(conv1_w, conv2_w, Wt1, Wt2);
    sums_kernel<<<1, 64, 0, stream>>>(ln2_g, ln2_b, lin_w, sums);

    conv_mfma_kernel<false><<<256, 512, 0, stream>>>(
        Xp, Wt1, conv1_b, ln1_g, ln1_b, H1p,
        nullptr, nullptr, nullptr, nullptr, nullptr);
    conv_mfma_kernel<true><<<256, 512, 0, stream>>>(
        H1p, Wt2, conv2_b, ln2_g, ln2_b, nullptr,
        lin_w, lin_b, sums, src_lens, log_dur);

    scan_kernel<<<B_, 256, 0, stream>>>(duration, src_lens, csum, idx, use_idx,
                                        dur_out, tlen_out, tmask);
    if (use_idx)
        expand_idx_kernel<<<B_ * ML_ / 2, 256, 0, stream>>>(x, csum, idx, expanded);
    else
        expand_kernel<<<B_ * ML_ / 2, 256, 0, stream>>>(x, csum, expanded);
}

// Round 5
// 482.475 us; speedup vs baseline: 3.5045x; 1.0324x over previous
//
#include <hip/hip_runtime.h>
#include <hip/hip_bf16.h>

#define B_  32
#define S_  1024
#define H_  512      // == F
#define ML_ 4096

typedef short short8 __attribute__((ext_vector_type(8)));
typedef float floatx4 __attribute__((ext_vector_type(4)));

// ---- output layout (flat float32 view) ----
constexpr size_t OFF_LOGDUR = (size_t)B_ * ML_ * H_;        // 67108864
constexpr size_t OFF_DUR    = OFF_LOGDUR + (size_t)B_ * S_;
constexpr size_t OFF_TLEN   = OFF_DUR + (size_t)B_ * S_;
constexpr size_t OFF_TMASK  = OFF_TLEN + B_;

// ---- scratch staged inside d_out's expanded region (bytes) ----
constexpr size_t XP_BYTES = (size_t)B_ * 1026 * 512 * 2;    // 33,619,968
constexpr size_t WT_BYTES = (size_t)3 * 512 * 512 * 2;      // 1,572,864
constexpr size_t OFF_XP   = 0;
constexpr size_t OFF_H1P  = XP_BYTES;
constexpr size_t OFF_WT1  = 2 * XP_BYTES;
constexpr size_t OFF_WT2  = 2 * XP_BYTES + WT_BYTES;        // ends ~70.4 MB < 268 MB

// ---- d_ws layout (bytes) ----
constexpr size_t WS_CSUM = 0;                                // 131072
constexpr size_t WS_SUMS = 131072;                           // 8 B
constexpr size_t WS_IDX  = 132096;                           // 524288
constexpr size_t WS_NEED_IDX = WS_IDX + (size_t)B_ * ML_ * 4;

__device__ __forceinline__ float wave_red(float v) {
#pragma unroll
    for (int o = 32; o > 0; o >>= 1) v += __shfl_down(v, o, 64);
    return v;
}

__device__ __forceinline__ unsigned short f2b(float f) {
    __hip_bfloat16 h = __float2bfloat16(f);
    return *reinterpret_cast<unsigned short*>(&h);
}

__device__ __forceinline__ void gld16(const void* g, void* l) {
    __builtin_amdgcn_global_load_lds(
        (const __attribute__((address_space(1))) unsigned int*)g,
        (__attribute__((address_space(3))) unsigned int*)l, 16, 0, 0);
}

// Pipelined sync primitives: NEVER let the compiler insert vmcnt(0) drains.
__device__ __forceinline__ void wait8_barrier() {
    asm volatile("s_waitcnt vmcnt(8)\n\ts_barrier" ::: "memory");
}
__device__ __forceinline__ void wait0_barrier() {
    asm volatile("s_waitcnt vmcnt(0)\n\ts_barrier" ::: "memory");
}
__device__ __forceinline__ void exec_barrier() {
    asm volatile("s_barrier" ::: "memory");
}

// ===================== prep kernels =====================

__global__ __launch_bounds__(256) void cast_x_kernel(
    const float* __restrict__ x, unsigned short* __restrict__ Xp,
    unsigned short* __restrict__ H1p) {
    const int tid = threadIdx.x;
    if (blockIdx.x < 8192) {
        size_t gid = (size_t)blockIdx.x * 256 + tid;
        size_t i8  = gid * 8;
        int row = (int)(i8 >> 9);
        int col = (int)(i8 & 511);
        int b = row >> 10, s = row & 1023;
        float4 v0 = *(const float4*)(x + i8);
        float4 v1 = *(const float4*)(x + i8 + 4);
        unsigned short u[8];
        u[0] = f2b(v0.x); u[1] = f2b(v0.y); u[2] = f2b(v0.z); u[3] = f2b(v0.w);
        u[4] = f2b(v1.x); u[5] = f2b(v1.y); u[6] = f2b(v1.z); u[7] = f2b(v1.w);
        *(uint4*)(Xp + ((size_t)b * 1026 + 1 + s) * 512 + col) = *(const uint4*)u;
    } else {
        int slot = (blockIdx.x - 8192) * 256 + tid;
        int row  = slot >> 6, seg = slot & 63;
        unsigned short* p = (row >> 6) ? H1p : Xp;
        int rr = row & 63;
        int b = rr >> 1, r = (rr & 1) ? 1025 : 0;
        uint4 z; z.x = 0; z.y = 0; z.z = 0; z.w = 0;
        *(uint4*)(p + ((size_t)(b * 1026 + r)) * 512 + seg * 8) = z;
    }
}

__global__ __launch_bounds__(256) void transpose_w_kernel(
    const float* __restrict__ W1, const float* __restrict__ W2,
    unsigned short* __restrict__ Wt1, unsigned short* __restrict__ Wt2) {
    __shared__ float t[32][33];
    int z = blockIdx.z;
    const float* W = (z < 3) ? W1 : W2;
    unsigned short* Wt = (z < 3) ? Wt1 : Wt2;
    int k  = (z < 3) ? z : z - 3;
    int h0 = blockIdx.x * 32, f0 = blockIdx.y * 32;
    int tx = threadIdx.x & 31, ty = threadIdx.x >> 5;
    const float* Wk = W + (size_t)k * 512 * 512;
    unsigned short* Wtk = Wt + (size_t)k * 512 * 512;
#pragma unroll
    for (int i = 0; i < 4; ++i)
        t[ty + 8 * i][tx] = Wk[(size_t)(h0 + ty + 8 * i) * 512 + f0 + tx];
    __syncthreads();
#pragma unroll
    for (int i = 0; i < 4; ++i)
        Wtk[(size_t)(f0 + ty + 8 * i) * 512 + h0 + tx] = f2b(t[tx][ty + 8 * i]);
}

__global__ __launch_bounds__(64) void sums_kernel(
    const float* __restrict__ g, const float* __restrict__ be,
    const float* __restrict__ lw, float* __restrict__ out) {
    int t = threadIdx.x;
    float a = 0.f, c = 0.f;
    for (int f = t; f < 512; f += 64) { a += g[f] * lw[f]; c += be[f] * lw[f]; }
    a = wave_red(a); c = wave_red(c);
    if (t == 0) { out[0] = a; out[1] = c; }
}

// ===================== fused conv+bias+ReLU+LN (bf16 MFMA, pipelined) ========
// Block: 512 threads (8 waves), tile M=128 x N=512. Grid 256 = 1 block/CU.
// K-loop: 24 chunks; B-tile (64 KB, dominant) double-buffered, prefetched one
// chunk ahead; in-loop syncs are inline-asm s_waitcnt vmcnt(8)+s_barrier so
// the prefetch stays in flight across the barrier (no vmcnt(0) drain).
template <bool LOGDUR>
__global__ __launch_bounds__(512, 2) void conv_mfma_kernel(
    const unsigned short* __restrict__ Xp,   // [B][1026][512] padded bf16
    const unsigned short* __restrict__ Wt,   // [3][512][512] f-major bf16
    const float* __restrict__ bias,
    const float* __restrict__ gamma,
    const float* __restrict__ beta,
    unsigned short* __restrict__ Op,         // conv1: padded bf16 out
    const float* __restrict__ lin_w,
    const float* __restrict__ lin_b,
    const float* __restrict__ sums,          // [0]=sum(g*lw) [1]=sum(be*lw)
    const int* __restrict__ src_lens,
    float* __restrict__ log_dur) {
    __shared__ __align__(16) unsigned char As[16384];    // 128 rows x 128 B (+red alias)
    __shared__ __align__(16) unsigned char Bs[131072];   // 2 x 64 KB ping-pong

    const int tid  = threadIdx.x;
    const int w    = tid >> 6;
    const int lane = tid & 63;
    const int lr   = lane & 15;
    const int lg   = lane >> 4;
    const int b    = blockIdx.x >> 3;
    const int sb   = (blockIdx.x & 7) * 128;
    const int phase = (blockIdx.x >> 3) % 24;

    const unsigned short* Xblk = Xp + ((size_t)b * 1026 + sb) * 512;

    floatx4 acc[8][4];
#pragma unroll
    for (int mt = 0; mt < 8; ++mt)
#pragma unroll
        for (int nt = 0; nt < 4; ++nt) acc[mt][nt] = (floatx4){0.f, 0.f, 0.f, 0.f};

    // ---- stage helpers (per wave: B = 8 gld16, A = 2 gld16) ----
    auto stageB = [&](int kk, int buf) {
        const int k  = kk >> 3;
        const int hc = (kk & 7) * 64;
        const unsigned short* Wk = Wt + (size_t)k * 512 * 512;
        unsigned char* dst = Bs + buf * 65536;
#pragma unroll
        for (int j2 = 0; j2 < 8; ++j2) {
            int fbase = w * 64 + j2 * 8;
            int f  = fbase + (lane >> 3);
            int cg = (lane & 7) ^ (f & 7);
            gld16(Wk + (size_t)f * 512 + hc + cg * 8, dst + fbase * 128);
        }
    };
    auto stageA = [&](int kk) {
        const int k  = kk >> 3;
        const int hc = (kk & 7) * 64;
#pragma unroll
        for (int j2 = 0; j2 < 2; ++j2) {
            int rowbase = w * 16 + j2 * 8;
            int row = rowbase + (lane >> 3);
            int cg  = (lane & 7) ^ (row & 7);
            gld16(Xblk + (size_t)(row + k) * 512 + hc + cg * 8, As + rowbase * 128);
        }
    };

    // ---- prologue: chunk ord(0) in flight (10 loads/wave) ----
    int kk0_ord = phase;                       // ord(i) = (i+phase) % 24
    stageA(kk0_ord);
    stageB(kk0_ord, 0);

    int buf = 0;
    int kk_cur = kk0_ord;
    for (int i = 0; i < 24; ++i) {
        // prefetch next B chunk into the other buffer (8 loads/wave)
        int kk_next = kk_cur + 1; if (kk_next >= 24) kk_next -= 24;
        if (i < 23) {
            stageB(kk_next, buf ^ 1);
            wait8_barrier();   // B(cur)+A(cur) landed; B(next) still in flight
        } else {
            wait0_barrier();
        }
        // ---- compute on As + Bs[buf] ----
        const unsigned char* Bbuf = Bs + buf * 65536;
#pragma unroll
        for (int j = 0; j < 2; ++j) {
            const int xt = ((j * 4 + lg) ^ (lr & 7)) * 16;
            short8 af[8], bf[4];
#pragma unroll
            for (int mt = 0; mt < 8; ++mt)
                af[mt] = *(const short8*)(As + (mt * 16 + lr) * 128 + xt);
#pragma unroll
            for (int nt = 0; nt < 4; ++nt)
                bf[nt] = *(const short8*)(Bbuf + (w * 64 + nt * 16 + lr) * 128 + xt);
#pragma unroll
            for (int mt = 0; mt < 8; ++mt)
#pragma unroll
                for (int nt = 0; nt < 4; ++nt)
                    acc[mt][nt] = __builtin_amdgcn_mfma_f32_16x16x32_bf16(
                        af[mt], bf[nt], acc[mt][nt], 0, 0, 0);
        }
        if (i < 23) {
            exec_barrier();    // all waves done reading As (WAR) — no drain
            stageA(kk_next);   // 2 loads/wave; waited by next iter's vmcnt(8)
        }
        buf ^= 1;
        kk_cur = kk_next;
    }
    __syncthreads();           // nothing outstanding; protect As reuse as red[]

    // red arrays aliased into As (dead after K-loop): 3 x 128 x 8 floats
    float (*red1)[8] = (float(*)[8])(As);
    float (*red2)[8] = (float(*)[8])(As + 4096);
    float (*red3)[8] = (float(*)[8])(As + 8192);

    // ---- epilogue: bias + ReLU, per-row stats ----
    float bia[4], gam[4], bet[4], glw[4];
#pragma unroll
    for (int nt = 0; nt < 4; ++nt) {
        int f = w * 64 + nt * 16 + lr;
        bia[nt] = bias[f]; gam[nt] = gamma[f]; bet[nt] = beta[f];
        if (LOGDUR) glw[nt] = gam[nt] * lin_w[f];
    }
#pragma unroll
    for (int mt = 0; mt < 8; ++mt)
#pragma unroll
        for (int nt = 0; nt < 4; ++nt)
#pragma unroll
            for (int r = 0; r < 4; ++r)
                acc[mt][nt][r] = fmaxf(acc[mt][nt][r] + bia[nt], 0.f);

#pragma unroll
    for (int mt = 0; mt < 8; ++mt)
#pragma unroll
        for (int r = 0; r < 4; ++r) {
            float p1 = 0.f, p2 = 0.f, p3 = 0.f;
#pragma unroll
            for (int nt = 0; nt < 4; ++nt) {
                float v = acc[mt][nt][r];
                p1 += v; p2 += v * v;
                if (LOGDUR) p3 += v * glw[nt];
            }
#pragma unroll
            for (int m = 1; m < 16; m <<= 1) {
                p1 += __shfl_xor(p1, m, 64);
                p2 += __shfl_xor(p2, m, 64);
                if (LOGDUR) p3 += __shfl_xor(p3, m, 64);
            }
            if (lr == 0) {
                int row = mt * 16 + lg * 4 + r;
                red1[row][w] = p1; red2[row][w] = p2;
                if (LOGDUR) red3[row][w] = p3;
            }
        }
    __syncthreads();

    if constexpr (!LOGDUR) {
        unsigned short* Oblk = Op + ((size_t)b * 1026 + 1 + sb) * 512;
#pragma unroll
        for (int half = 0; half < 2; ++half) {
#pragma unroll
            for (int mi = 0; mi < 4; ++mi) {
                int mt = half * 4 + mi;
#pragma unroll
                for (int r = 0; r < 4; ++r) {
                    int row = mt * 16 + lg * 4 + r;
                    float s1 = 0.f, s2 = 0.f;
#pragma unroll
                    for (int ww = 0; ww < 8; ++ww) { s1 += red1[row][ww]; s2 += red2[row][ww]; }
                    float mu = s1 * (1.f / 512.f);
                    float rstd = rsqrtf(s2 * (1.f / 512.f) - mu * mu + 1e-5f);
#pragma unroll
                    for (int nt = 0; nt < 4; ++nt) {
                        float y = (acc[mt][nt][r] - mu) * rstd * gam[nt] + bet[nt];
                        ((unsigned short*)Bs)[(row - half * 64) * 520 + w * 64 + nt * 16 + lr] = f2b(y);
                    }
                }
            }
            __syncthreads();
            for (int it = tid; it < 4096; it += 512) {
                int rr = it >> 6, seg = it & 63;
                uint4 v = *(const uint4*)(Bs + rr * 1040 + seg * 16);
                *(uint4*)(Oblk + (size_t)(half * 64 + rr) * 512 + seg * 8) = v;
            }
            __syncthreads();
        }
    } else {
        if (tid < 128) {
            int row = tid;
            float s1 = 0.f, s2 = 0.f, s3 = 0.f;
#pragma unroll
            for (int ww = 0; ww < 8; ++ww) {
                s1 += red1[row][ww]; s2 += red2[row][ww]; s3 += red3[row][ww];
            }
            float mu   = s1 * (1.f / 512.f);
            float rstd = rsqrtf(s2 * (1.f / 512.f) - mu * mu + 1e-5f);
            float val  = rstd * (s3 - mu * sums[0]) + sums[1] + lin_b[0];
            int s = sb + row;
            log_dur[b * S_ + s] = (s >= src_lens[b]) ? 0.f : val;
        }
    }
}

// ===================== scan (+ idx scatter) =====================

__global__ __launch_bounds__(256) void scan_kernel(
    const int* __restrict__ duration, const int* __restrict__ src_lens,
    int* __restrict__ csum, int* __restrict__ idx, int do_idx,
    float* __restrict__ dur_out, float* __restrict__ tlen_out,
    float* __restrict__ tmask_out) {
    const int b = blockIdx.x, t = threadIdx.x;
    __shared__ int lds[256];
    __shared__ int total_sh;

    const int slen = src_lens[b];
    int loc[4];
    const int sb = t * 4;
#pragma unroll
    for (int i = 0; i < 4; ++i) {
        int s = sb + i;
        loc[i] = (s < slen) ? duration[b * S_ + s] : 0;
    }
    int tsum = loc[0] + loc[1] + loc[2] + loc[3];

    lds[t] = tsum;
    __syncthreads();
    for (int off = 1; off < 256; off <<= 1) {
        int v = (t >= off) ? lds[t - off] : 0;
        __syncthreads();
        lds[t] += v;
        __syncthreads();
    }
    int incl = lds[t];
    if (t == 255) total_sh = incl;

    int run = incl - tsum;
#pragma unroll
    for (int i = 0; i < 4; ++i) {
        int start = run;
        run += loc[i];
        csum[b * S_ + sb + i]    = run;
        dur_out[b * S_ + sb + i] = (float)loc[i];
        if (do_idx)
            for (int q = start; q < run; ++q) idx[b * ML_ + q] = sb + i;
    }
    __syncthreads();
    const int total = total_sh;
    if (t == 0) tlen_out[b] = (float)total;
    for (int p = t; p < ML_; p += 256) tmask_out[b * ML_ + p] = (p >= total) ? 1.f : 0.f;
}

// ===================== expand =====================

__global__ __launch_bounds__(256) void expand_idx_kernel(
    const float* __restrict__ x, const int* __restrict__ csum,
    const int* __restrict__ idx, float* __restrict__ out) {
    const int tid  = threadIdx.x;
    const int row  = blockIdx.x * 2 + (tid >> 7);
    const int lane = tid & 127;
    const int b = row >> 12;
    const int p = row & (ML_ - 1);
    const int total = csum[b * S_ + S_ - 1];
    float4 v = make_float4(0.f, 0.f, 0.f, 0.f);
    if (p < total) {
        int ir = idx[b * ML_ + p];
        v = ((const float4*)x)[(size_t)(b * S_ + ir) * (H_ / 4) + lane];
    }
    ((float4*)out)[(size_t)row * (H_ / 4) + lane] = v;
}

__global__ __launch_bounds__(256) void expand_kernel(
    const float* __restrict__ x, const int* __restrict__ csum,
    float* __restrict__ out) {
    const int tid  = threadIdx.x;
    const int row  = blockIdx.x * 2 + (tid >> 7);
    const int lane = tid & 127;
    const int b = row >> 12;
    const int p = row & (ML_ - 1);
    const int* cs = csum + b * S_;
    const int total = cs[S_ - 1];
    int lo = 0, hi = S_;
    while (lo < hi) {
        int mid = (lo + hi) >> 1;
        if (cs[mid] <= p) lo = mid + 1; else hi = mid;
    }
    int ir = lo < (S_ - 1) ? lo : (S_ - 1);
    float4 v = make_float4(0.f, 0.f, 0.f, 0.f);
    if (p < total) v = ((const float4*)x)[(size_t)(b * S_ + ir) * (H_ / 4) + lane];
    ((float4*)out)[(size_t)row * (H_ / 4) + lane] = v;
}

// ===================== launch =====================

extern "C" void kernel_launch(void* const* d_in, const int* in_sizes, int n_in,
                              void* d_out, int out_size, void* d_ws, size_t ws_size,
                              hipStream_t stream) {
    const float* x        = (const float*)d_in[0];
    const int*   duration = (const int*)d_in[1];
    const int*   src_lens = (const int*)d_in[2];
    const float* conv1_w = (const float*)d_in[4];
    const float* conv1_b = (const float*)d_in[5];
    const float* ln1_g   = (const float*)d_in[6];
    const float* ln1_b   = (const float*)d_in[7];
    const float* conv2_w = (const float*)d_in[8];
    const float* conv2_b = (const float*)d_in[9];
    const float* ln2_g   = (const float*)d_in[10];
    const float* ln2_b   = (const float*)d_in[11];
    const float* lin_w   = (const float*)d_in[12];
    const float* lin_b   = (const float*)d_in[13];

    float* out      = (float*)d_out;
    float* expanded = out;
    float* log_dur  = out + OFF_LOGDUR;
    float* dur_out  = out + OFF_DUR;
    float* tlen_out = out + OFF_TLEN;
    float* tmask    = out + OFF_TMASK;

    int*   csum = (int*)((char*)d_ws + WS_CSUM);
    float* sums = (float*)((char*)d_ws + WS_SUMS);
    int*   idx  = (int*)((char*)d_ws + WS_IDX);
    const int use_idx = (ws_size >= WS_NEED_IDX) ? 1 : 0;

    unsigned short* Xp  = (unsigned short*)((char*)d_out + OFF_XP);
    unsigned short* H1p = (unsigned short*)((char*)d_out + OFF_H1P);
    unsigned short* Wt1 = (unsigned short*)((char*)d_out + OFF_WT1);
    unsigned short* Wt2 = (unsigned short*)((char*)d_out + OFF_WT2);

    cast_x_kernel<<<8224, 256, 0, stream>>>(x, Xp, H1p);
    transpose_w_kernel<<<dim3(16, 16, 6), 256, 0, stream>>>(conv1_w, conv2_w, Wt1, Wt2);
    sums_kernel<<<1, 64, 0, stream>>>(ln2_g, ln2_b, lin_w, sums);

    conv_mfma_kernel<false><<<256, 512, 0, stream>>>(
        Xp, Wt1, conv1_b, ln1_g, ln1_b, H1p,
        nullptr, nullptr, nullptr, nullptr, nullptr);
    conv_mfma_kernel<true><<<256, 512, 0, stream>>>(
        H1p, Wt2, conv2_b, ln2_g, ln2_b, nullptr,
        lin_w, lin_b, sums, src_lens, log_dur);

    scan_kernel<<<B_, 256, 0, stream>>>(duration, src_lens, csum, idx, use_idx,
                                        dur_out, tlen_out, tmask);
    if (use_idx)
        expand_idx_kernel<<<B_ * ML_ / 2, 256, 0, stream>>>(x, csum, idx, expanded);
    else
        expand_kernel<<<B_ * ML_ / 2, 256, 0, stream>>>(x, csum, expanded);
}